// Round 3
// baseline (217.710 us; speedup 1.0000x reference)
//
#include <hip/hip_runtime.h>

// Attention 8192x8192, D=DV=64, fp32 in/out.
// R3: prepass converts K->bf16 and V->bf16-transposed into d_ws; main kernel
// loads MFMA fragments directly from global (no K/V LDS, barrier-free K-loop),
// 32 rows/wave, 8-way key split, fixed-offset softmax, ones-MFMA row sums.

#define NQ 8192
#define NK 8192

typedef float f32x4 __attribute__((ext_vector_type(4)));
typedef short short8 __attribute__((ext_vector_type(8)));
union U4 { uint4 u; short8 s; };

#define MFMA16 __builtin_amdgcn_mfma_f32_16x16x32_bf16

// round-to-nearest-even fp32->bf16 pair pack (lo = a)
__device__ __forceinline__ unsigned pk2(float a, float b) {
    unsigned ua = __builtin_bit_cast(unsigned, a);
    unsigned ub = __builtin_bit_cast(unsigned, b);
    ua = (ua + 0x7FFFu + ((ua >> 16) & 1u)) >> 16;
    ub = (ub + 0x7FFFu + ((ub >> 16) & 1u)) & 0xFFFF0000u;
    return ua | ub;
}

// ---- prepass: K fp32 -> bf16 (same layout), V fp32 -> bf16 transposed ----
__global__ __launch_bounds__(256)
void prepass(const float* __restrict__ Kg, const float* __restrict__ Vg,
             unsigned short* __restrict__ Kb, unsigned short* __restrict__ Vt) {
    __shared__ float ld[64 * 33];
    const int t = threadIdx.x, b = blockIdx.x;

    // K convert: rows b*32 .. b*32+31
    {
        const int row = b * 32 + (t >> 3), dg = t & 7;
        const float* gp = Kg + (size_t)row * 64 + dg * 8;
        float4 f0 = *(const float4*)gp;
        float4 f1 = *(const float4*)(gp + 4);
        uint4 o = make_uint4(pk2(f0.x, f0.y), pk2(f0.z, f0.w),
                             pk2(f1.x, f1.y), pk2(f1.z, f1.w));
        *(uint4*)(Kb + (size_t)row * 64 + dg * 8) = o;
    }
    // V transpose: keys b*32 .. b*32+31 -> Vt[dim][key]
    {
        const int key = t >> 3, dg = t & 7;
        const float* gp = Vg + (size_t)(b * 32 + key) * 64 + dg * 8;
        float4 f0 = *(const float4*)gp;
        float4 f1 = *(const float4*)(gp + 4);
        ld[(dg * 8 + 0) * 33 + key] = f0.x;
        ld[(dg * 8 + 1) * 33 + key] = f0.y;
        ld[(dg * 8 + 2) * 33 + key] = f0.z;
        ld[(dg * 8 + 3) * 33 + key] = f0.w;
        ld[(dg * 8 + 4) * 33 + key] = f1.x;
        ld[(dg * 8 + 5) * 33 + key] = f1.y;
        ld[(dg * 8 + 6) * 33 + key] = f1.z;
        ld[(dg * 8 + 7) * 33 + key] = f1.w;
    }
    __syncthreads();
    {
        const int dim = t >> 2, kq = t & 3;
        float v[8];
        #pragma unroll
        for (int j = 0; j < 8; ++j) v[j] = ld[dim * 33 + kq * 8 + j];
        uint4 o = make_uint4(pk2(v[0], v[1]), pk2(v[2], v[3]),
                             pk2(v[4], v[5]), pk2(v[6], v[7]));
        *(uint4*)(Vt + (size_t)dim * 8192 + b * 32 + kq * 8) = o;
    }
}

// ---- main kernel ----
__global__ __launch_bounds__(512, 2)
void attn_main(const float* __restrict__ Qg,
               const unsigned short* __restrict__ Kb,
               const unsigned short* __restrict__ Vt,
               float* __restrict__ Og) {
    // shb4[0..1023]: P regions, 16 x 64 uint4 ([w][rt]); epilogue reuses all.
    __shared__ uint4 shb4[2080];            // 33280 B
    float* sF = (float*)shb4;
    unsigned* shu = (unsigned*)shb4;

    const int t = threadIdx.x, w = t >> 6, lane = t & 63;
    const int q = lane >> 4, i16 = lane & 15;
    const int qb0 = blockIdx.x * 32;

    // Q fragments (scale 1/8 * log2 e folded)
    const float SCL = 0.18033688011112042f;
    short8 aq[2][2];
    #pragma unroll
    for (int rt = 0; rt < 2; ++rt) {
        const float* qp = Qg + (size_t)(qb0 + rt * 16 + i16) * 64 + q * 8;
        #pragma unroll
        for (int h = 0; h < 2; ++h) {
            float4 f0 = *(const float4*)(qp + h * 32);
            float4 f1 = *(const float4*)(qp + h * 32 + 4);
            U4 u;
            u.u = make_uint4(pk2(f0.x * SCL, f0.y * SCL), pk2(f0.z * SCL, f0.w * SCL),
                             pk2(f1.x * SCL, f1.y * SCL), pk2(f1.z * SCL, f1.w * SCL));
            aq[rt][h] = u.s;
        }
    }
    short8 bones;
    { U4 u; u.u = make_uint4(0x3F803F80u, 0x3F803F80u, 0x3F803F80u, 0x3F803F80u); bones = u.s; }

    f32x4 acc[2][4];
    f32x4 lacc[2];
    #pragma unroll
    for (int rt = 0; rt < 2; ++rt) {
        #pragma unroll
        for (int dt = 0; dt < 4; ++dt) { acc[rt][dt][0]=0.f; acc[rt][dt][1]=0.f; acc[rt][dt][2]=0.f; acc[rt][dt][3]=0.f; }
        lacc[rt][0]=0.f; lacc[rt][1]=0.f; lacc[rt][2]=0.f; lacc[rt][3]=0.f;
    }

    // P slot indices (verified conflict-free in R2)
    const int tpw = ((i16 >> 2) & 1) + 2 * q + 32 * (i16 >> 3);  // tp = tpw + 8r
    const int pp  = i16 & 3;
    const int tpr = (q & 1) + 2 * ((i16 >> 2) & 3) + 8 * (i16 & 3) + 32 * (q >> 1);

    uint4 kf[2][4], vf[2][4];
    #define LOAD_TILE(TT, KD, VD)                                                        \
        do {                                                                             \
            const int kb_ = (TT) * 256;                                                  \
            _Pragma("unroll")                                                            \
            for (int e = 0; e < 2; ++e)                                                  \
                _Pragma("unroll")                                                        \
                for (int h = 0; h < 2; ++h)                                              \
                    (KD)[e * 2 + h] = *(const uint4*)(Kb +                               \
                        ((size_t)(kb_ + w * 32 + 2 * i16 + e) << 6) + h * 32 + q * 8);   \
            _Pragma("unroll")                                                            \
            for (int dt = 0; dt < 4; ++dt)                                               \
                (VD)[dt] = *(const uint4*)(Vt + (size_t)(dt * 16 + i16) * 8192 +         \
                                           kb_ + w * 32 + q * 8);                        \
        } while (0)

    LOAD_TILE(0, kf[0], vf[0]);

    for (int tt = 0; tt < 32; ++tt) {
        const int b = tt & 1;
        if (tt < 31) LOAD_TILE(tt + 1, kf[b ^ 1], vf[b ^ 1]);

        // QK^T
        f32x4 sfr[2][2];
        #pragma unroll
        for (int rt = 0; rt < 2; ++rt)
            #pragma unroll
            for (int e = 0; e < 2; ++e) {
                f32x4 sacc; sacc[0]=0.f; sacc[1]=0.f; sacc[2]=0.f; sacc[3]=0.f;
                #pragma unroll
                for (int h = 0; h < 2; ++h) {
                    U4 u; u.u = kf[b][e * 2 + h];
                    sacc = MFMA16(aq[rt][h], u.s, sacc, 0, 0, 0);
                }
                sfr[rt][e] = sacc;
            }

        // exp2 (fixed offset), pack adjacent-key pairs into per-wave P region
        #pragma unroll
        for (int rt = 0; rt < 2; ++rt) {
            const int rbase = (w * 2 + rt) * 256;   // dword base of region
            #pragma unroll
            for (int r = 0; r < 4; ++r) {
                float p0 = __builtin_amdgcn_exp2f(sfr[rt][0][r] - 16.0f);
                float p1 = __builtin_amdgcn_exp2f(sfr[rt][1][r] - 16.0f);
                shu[rbase + (tpw + 8 * r) * 4 + pp] = pk2(p0, p1);
            }
        }
        U4 ap[2];
        #pragma unroll
        for (int rt = 0; rt < 2; ++rt) ap[rt].u = shb4[(w * 2 + rt) * 64 + tpr];

        // row sums + PV
        #pragma unroll
        for (int rt = 0; rt < 2; ++rt) {
            lacc[rt] = MFMA16(ap[rt].s, bones, lacc[rt], 0, 0, 0);
            #pragma unroll
            for (int dt = 0; dt < 4; ++dt) {
                U4 bv; bv.u = vf[b][dt];
                acc[rt][dt] = MFMA16(ap[rt].s, bv.s, acc[rt][dt], 0, 0, 0);
            }
        }
    }

    // ---- tree-merge the 8 key-split partials ----
    __syncthreads();
    for (int step = 4; step >= 1; step >>= 1) {
        if (w >= step && w < 2 * step) {
            float* base = sF + (w - step) * 2080;
            #pragma unroll
            for (int rt = 0; rt < 2; ++rt) {
                #pragma unroll
                for (int dt = 0; dt < 4; ++dt)
                    #pragma unroll
                    for (int r = 0; r < 4; ++r)
                        base[(rt * 16 + 4 * q + r) * 64 + dt * 16 + i16] = acc[rt][dt][r];
                if (i16 == 0) {
                    #pragma unroll
                    for (int r = 0; r < 4; ++r) base[2048 + rt * 16 + 4 * q + r] = lacc[rt][r];
                }
            }
        }
        __syncthreads();
        if (w < step) {
            const float* base = sF + w * 2080;
            #pragma unroll
            for (int rt = 0; rt < 2; ++rt) {
                #pragma unroll
                for (int dt = 0; dt < 4; ++dt)
                    #pragma unroll
                    for (int r = 0; r < 4; ++r)
                        acc[rt][dt][r] += base[(rt * 16 + 4 * q + r) * 64 + dt * 16 + i16];
                #pragma unroll
                for (int r = 0; r < 4; ++r) lacc[rt][r] += base[2048 + rt * 16 + 4 * q + r];
            }
        }
        __syncthreads();
    }

    // wave 0 normalizes into LDS; whole block stores float4
    if (w == 0) {
        #pragma unroll
        for (int rt = 0; rt < 2; ++rt)
            #pragma unroll
            for (int r = 0; r < 4; ++r) {
                const float inv = 1.0f / lacc[rt][r];
                #pragma unroll
                for (int dt = 0; dt < 4; ++dt)
                    sF[(rt * 16 + 4 * q + r) * 64 + dt * 16 + i16] = acc[rt][dt][r] * inv;
            }
    }
    __syncthreads();
    {
        const int row = t >> 4, ds = t & 15;
        float4 o = *(const float4*)(sF + row * 64 + ds * 4);
        *(float4*)(Og + (size_t)(qb0 + row) * 64 + ds * 4) = o;
    }
}

extern "C" void kernel_launch(void* const* d_in, const int* in_sizes, int n_in,
                              void* d_out, int out_size, void* d_ws, size_t ws_size,
                              hipStream_t stream) {
    const float* Q = (const float*)d_in[0];
    const float* K = (const float*)d_in[1];
    const float* V = (const float*)d_in[2];
    float* O = (float*)d_out;
    unsigned short* Kb = (unsigned short*)d_ws;                       // 1 MB
    unsigned short* Vt = (unsigned short*)((char*)d_ws + (1 << 20));  // 1 MB
    hipLaunchKernelGGL(prepass, dim3(256), dim3(256), 0, stream, K, V, Kb, Vt);
    hipLaunchKernelGGL(attn_main, dim3(NQ / 32), dim3(512), 0, stream, Q, Kb, Vt, O);
}

// Round 4
// 122.505 us; speedup vs baseline: 1.7772x; 1.7772x over previous
//
#include <hip/hip_runtime.h>

// Attention 8192x8192, D=DV=64, fp32 in/out.
// R4: R3 structure with the scratch-spill fixed — explicit ping-pong fragment
// buffers, no runtime-indexed local arrays. Prepass converts K->bf16 and
// V->bf16-transposed into d_ws; main kernel loads MFMA fragments directly from
// global (L2-resident), barrier-free K-loop, 32 rows/wave, 8-way key split,
// fixed-offset softmax (offset folded into QK acc init), ones-MFMA row sums.

#define NQ 8192
#define NK 8192

typedef float f32x4 __attribute__((ext_vector_type(4)));
typedef short short8 __attribute__((ext_vector_type(8)));
union U4 { uint4 u; short8 s; };

#define MFMA16 __builtin_amdgcn_mfma_f32_16x16x32_bf16

// round-to-nearest-even fp32->bf16 pair pack (lo = a)
__device__ __forceinline__ unsigned pk2(float a, float b) {
    unsigned ua = __builtin_bit_cast(unsigned, a);
    unsigned ub = __builtin_bit_cast(unsigned, b);
    ua = (ua + 0x7FFFu + ((ua >> 16) & 1u)) >> 16;
    ub = (ub + 0x7FFFu + ((ub >> 16) & 1u)) & 0xFFFF0000u;
    return ua | ub;
}

// ---- prepass: K fp32 -> bf16 (same layout), V fp32 -> bf16 transposed ----
__global__ __launch_bounds__(256)
void prepass(const float* __restrict__ Kg, const float* __restrict__ Vg,
             unsigned short* __restrict__ Kb, unsigned short* __restrict__ Vt) {
    __shared__ float ld[64 * 33];
    const int t = threadIdx.x, b = blockIdx.x;

    // K convert: rows b*32 .. b*32+31
    {
        const int row = b * 32 + (t >> 3), dg = t & 7;
        const float* gp = Kg + (size_t)row * 64 + dg * 8;
        float4 f0 = *(const float4*)gp;
        float4 f1 = *(const float4*)(gp + 4);
        uint4 o = make_uint4(pk2(f0.x, f0.y), pk2(f0.z, f0.w),
                             pk2(f1.x, f1.y), pk2(f1.z, f1.w));
        *(uint4*)(Kb + (size_t)row * 64 + dg * 8) = o;
    }
    // V transpose: keys b*32 .. b*32+31 -> Vt[dim][key]
    {
        const int key = t >> 3, dg = t & 7;
        const float* gp = Vg + (size_t)(b * 32 + key) * 64 + dg * 8;
        float4 f0 = *(const float4*)gp;
        float4 f1 = *(const float4*)(gp + 4);
        ld[(dg * 8 + 0) * 33 + key] = f0.x;
        ld[(dg * 8 + 1) * 33 + key] = f0.y;
        ld[(dg * 8 + 2) * 33 + key] = f0.z;
        ld[(dg * 8 + 3) * 33 + key] = f0.w;
        ld[(dg * 8 + 4) * 33 + key] = f1.x;
        ld[(dg * 8 + 5) * 33 + key] = f1.y;
        ld[(dg * 8 + 6) * 33 + key] = f1.z;
        ld[(dg * 8 + 7) * 33 + key] = f1.w;
    }
    __syncthreads();
    {
        const int dim = t >> 2, kq = t & 3;
        float v[8];
        #pragma unroll
        for (int j = 0; j < 8; ++j) v[j] = ld[dim * 33 + kq * 8 + j];
        uint4 o = make_uint4(pk2(v[0], v[1]), pk2(v[2], v[3]),
                             pk2(v[4], v[5]), pk2(v[6], v[7]));
        *(uint4*)(Vt + (size_t)dim * 8192 + b * 32 + kq * 8) = o;
    }
}

// ---- main kernel ----
__global__ __launch_bounds__(512, 1)
void attn_main(const float* __restrict__ Qg,
               const unsigned short* __restrict__ Kb,
               const unsigned short* __restrict__ Vt,
               float* __restrict__ Og) {
    // shb4[0..1023]: P regions, 16 x 64 uint4 ([w][rt]); epilogue reuses all.
    __shared__ uint4 shb4[2080];            // 33280 B
    float* sF = (float*)shb4;
    unsigned* shu = (unsigned*)shb4;

    const int t = threadIdx.x, w = t >> 6, lane = t & 63;
    const int q = lane >> 4, i16 = lane & 15;
    const int qb0 = blockIdx.x * 32;

    // Q fragments (scale 1/8 * log2 e folded)
    const float SCL = 0.18033688011112042f;
    short8 aq0, aq1, aq2, aq3;   // [rt][h]: aq0=rt0h0 aq1=rt0h1 aq2=rt1h0 aq3=rt1h1
    {
        const float* qp0 = Qg + (size_t)(qb0 + i16) * 64 + q * 8;
        const float* qp1 = Qg + (size_t)(qb0 + 16 + i16) * 64 + q * 8;
        U4 u;
        float4 f0, f1;
        f0 = *(const float4*)(qp0);      f1 = *(const float4*)(qp0 + 4);
        u.u = make_uint4(pk2(f0.x * SCL, f0.y * SCL), pk2(f0.z * SCL, f0.w * SCL),
                         pk2(f1.x * SCL, f1.y * SCL), pk2(f1.z * SCL, f1.w * SCL));
        aq0 = u.s;
        f0 = *(const float4*)(qp0 + 32); f1 = *(const float4*)(qp0 + 36);
        u.u = make_uint4(pk2(f0.x * SCL, f0.y * SCL), pk2(f0.z * SCL, f0.w * SCL),
                         pk2(f1.x * SCL, f1.y * SCL), pk2(f1.z * SCL, f1.w * SCL));
        aq1 = u.s;
        f0 = *(const float4*)(qp1);      f1 = *(const float4*)(qp1 + 4);
        u.u = make_uint4(pk2(f0.x * SCL, f0.y * SCL), pk2(f0.z * SCL, f0.w * SCL),
                         pk2(f1.x * SCL, f1.y * SCL), pk2(f1.z * SCL, f1.w * SCL));
        aq2 = u.s;
        f0 = *(const float4*)(qp1 + 32); f1 = *(const float4*)(qp1 + 36);
        u.u = make_uint4(pk2(f0.x * SCL, f0.y * SCL), pk2(f0.z * SCL, f0.w * SCL),
                         pk2(f1.x * SCL, f1.y * SCL), pk2(f1.z * SCL, f1.w * SCL));
        aq3 = u.s;
    }
    short8 bones;
    { U4 u; u.u = make_uint4(0x3F803F80u, 0x3F803F80u, 0x3F803F80u, 0x3F803F80u); bones = u.s; }

    f32x4 acc[2][4];   // static indices only
    f32x4 lacc[2];
    #pragma unroll
    for (int rt = 0; rt < 2; ++rt) {
        #pragma unroll
        for (int dt = 0; dt < 4; ++dt) { acc[rt][dt][0]=0.f; acc[rt][dt][1]=0.f; acc[rt][dt][2]=0.f; acc[rt][dt][3]=0.f; }
        lacc[rt][0]=0.f; lacc[rt][1]=0.f; lacc[rt][2]=0.f; lacc[rt][3]=0.f;
    }

    // P slot indices (layout verified in R2/R3)
    const int tpw = ((i16 >> 2) & 1) + 2 * q + 32 * (i16 >> 3);  // tp = tpw + 8r
    const int pp  = i16 & 3;
    const int tpr = (q & 1) + 2 * ((i16 >> 2) & 3) + 8 * (i16 & 3) + 32 * (q >> 1);

    uint4 kf0[4], vf0[4], kf1[4], vf1[4];

#define LOAD_TILE(TT, KD, VD)                                                        \
    do {                                                                             \
        const int kb_ = (TT) * 256;                                                  \
        _Pragma("unroll")                                                            \
        for (int e = 0; e < 2; ++e)                                                  \
            _Pragma("unroll")                                                        \
            for (int h = 0; h < 2; ++h)                                              \
                (KD)[e * 2 + h] = *(const uint4*)(Kb +                               \
                    ((size_t)(kb_ + w * 32 + 2 * i16 + e) << 6) + h * 32 + q * 8);   \
        _Pragma("unroll")                                                            \
        for (int dt = 0; dt < 4; ++dt)                                               \
            (VD)[dt] = *(const uint4*)(Vt + (size_t)(dt * 16 + i16) * 8192 +         \
                                       kb_ + w * 32 + q * 8);                        \
    } while (0)

#define COMPUTE(KD, VD)                                                              \
    do {                                                                             \
        f32x4 sfr[2][2];                                                             \
        _Pragma("unroll")                                                            \
        for (int rt = 0; rt < 2; ++rt)                                               \
            _Pragma("unroll")                                                        \
            for (int e = 0; e < 2; ++e) {                                            \
                f32x4 sacc;                                                          \
                sacc[0]=-16.f; sacc[1]=-16.f; sacc[2]=-16.f; sacc[3]=-16.f;          \
                U4 u0; u0.u = (KD)[e * 2 + 0];                                       \
                U4 u1; u1.u = (KD)[e * 2 + 1];                                       \
                sacc = MFMA16(rt ? aq2 : aq0, u0.s, sacc, 0, 0, 0);                  \
                sacc = MFMA16(rt ? aq3 : aq1, u1.s, sacc, 0, 0, 0);                  \
                sfr[rt][e] = sacc;                                                   \
            }                                                                        \
        _Pragma("unroll")                                                            \
        for (int rt = 0; rt < 2; ++rt) {                                             \
            const int rbase = (w * 2 + rt) * 256;                                    \
            _Pragma("unroll")                                                        \
            for (int r = 0; r < 4; ++r) {                                            \
                float p0 = __builtin_amdgcn_exp2f(sfr[rt][0][r]);                    \
                float p1 = __builtin_amdgcn_exp2f(sfr[rt][1][r]);                    \
                shu[rbase + (tpw + 8 * r) * 4 + pp] = pk2(p0, p1);                   \
            }                                                                        \
        }                                                                            \
        U4 ap0, ap1;                                                                 \
        ap0.u = shb4[(w * 2 + 0) * 64 + tpr];                                        \
        ap1.u = shb4[(w * 2 + 1) * 64 + tpr];                                        \
        lacc[0] = MFMA16(ap0.s, bones, lacc[0], 0, 0, 0);                            \
        lacc[1] = MFMA16(ap1.s, bones, lacc[1], 0, 0, 0);                            \
        _Pragma("unroll")                                                            \
        for (int dt = 0; dt < 4; ++dt) {                                             \
            U4 bv; bv.u = (VD)[dt];                                                  \
            acc[0][dt] = MFMA16(ap0.s, bv.s, acc[0][dt], 0, 0, 0);                   \
            acc[1][dt] = MFMA16(ap1.s, bv.s, acc[1][dt], 0, 0, 0);                   \
        }                                                                            \
    } while (0)

    LOAD_TILE(0, kf0, vf0);
    #pragma unroll 1
    for (int tt = 0; tt < 32; tt += 2) {
        LOAD_TILE(tt + 1, kf1, vf1);
        COMPUTE(kf0, vf0);
        LOAD_TILE((tt + 2) & 31, kf0, vf0);
        COMPUTE(kf1, vf1);
    }

    // ---- tree-merge the 8 key-split partials ----
    __syncthreads();
    for (int step = 4; step >= 1; step >>= 1) {
        if (w >= step && w < 2 * step) {
            float* base = sF + (w - step) * 2080;
            #pragma unroll
            for (int rt = 0; rt < 2; ++rt) {
                #pragma unroll
                for (int dt = 0; dt < 4; ++dt)
                    #pragma unroll
                    for (int r = 0; r < 4; ++r)
                        base[(rt * 16 + 4 * q + r) * 64 + dt * 16 + i16] = acc[rt][dt][r];
                if (i16 == 0) {
                    #pragma unroll
                    for (int r = 0; r < 4; ++r) base[2048 + rt * 16 + 4 * q + r] = lacc[rt][r];
                }
            }
        }
        __syncthreads();
        if (w < step) {
            const float* base = sF + w * 2080;
            #pragma unroll
            for (int rt = 0; rt < 2; ++rt) {
                #pragma unroll
                for (int dt = 0; dt < 4; ++dt)
                    #pragma unroll
                    for (int r = 0; r < 4; ++r)
                        acc[rt][dt][r] += base[(rt * 16 + 4 * q + r) * 64 + dt * 16 + i16];
                #pragma unroll
                for (int r = 0; r < 4; ++r) lacc[rt][r] += base[2048 + rt * 16 + 4 * q + r];
            }
        }
        __syncthreads();
    }

    // wave 0 normalizes into LDS; whole block stores float4
    if (w == 0) {
        #pragma unroll
        for (int rt = 0; rt < 2; ++rt)
            #pragma unroll
            for (int r = 0; r < 4; ++r) {
                const float inv = 1.0f / lacc[rt][r];
                #pragma unroll
                for (int dt = 0; dt < 4; ++dt)
                    sF[(rt * 16 + 4 * q + r) * 64 + dt * 16 + i16] = acc[rt][dt][r] * inv;
            }
    }
    __syncthreads();
    {
        const int row = t >> 4, ds = t & 15;
        float4 o = *(const float4*)(sF + row * 64 + ds * 4);
        *(float4*)(Og + (size_t)(qb0 + row) * 64 + ds * 4) = o;
    }
}

extern "C" void kernel_launch(void* const* d_in, const int* in_sizes, int n_in,
                              void* d_out, int out_size, void* d_ws, size_t ws_size,
                              hipStream_t stream) {
    const float* Q = (const float*)d_in[0];
    const float* K = (const float*)d_in[1];
    const float* V = (const float*)d_in[2];
    float* O = (float*)d_out;
    unsigned short* Kb = (unsigned short*)d_ws;                       // 1 MB
    unsigned short* Vt = (unsigned short*)((char*)d_ws + (1 << 20));  // 1 MB
    hipLaunchKernelGGL(prepass, dim3(256), dim3(256), 0, stream, K, V, Kb, Vt);
    hipLaunchKernelGGL(attn_main, dim3(NQ / 32), dim3(512), 0, stream, Q, Kb, Vt, O);
}